// Round 5
// baseline (361.016 us; speedup 1.0000x reference)
//
#include <hip/hip_runtime.h>

// ProjectionPursuitProbe: h' = scale * (h - P G^{-1} P^T h), G = P^T P
// B=8, S=4096, F=1024, R=64. Rows N = 32768.
//
// v6: invert off the critical path; everything else in-block.
//  - pp_gram (16 blocks): gram partials + Ptf/Pbf fragment-stream packing (v5, verified).
//  - pp_fused (513 blocks, 3 blocks/CU):
//      block 0: sum partials -> 4-wave Gauss-Jordan (v5-verified) -> Wf + release flag.
//      blocks 1..512: phase1 Y=H@P (register-direct, overlaps the invert) ->
//      acquire-spin on flag -> phase2 C=Y@W -> scale -> phase3 apply, all in-block
//      (no Cf/Sc global round-trip, no pp_apply launch).
//    Deadlock-free: capacity 768 blocks >= grid 513, so all blocks co-resident
//    regardless of dispatch order; producer block always resident.

typedef __attribute__((ext_vector_type(8))) short bf16x8;
typedef __attribute__((ext_vector_type(4))) float f32x4;

#define MFMA_B16(a, b, c) __builtin_amdgcn_mfma_f32_16x16x32_bf16((a), (b), (c), 0, 0, 0)

__device__ __forceinline__ unsigned short bf16bits(float x) {
  union { float f; unsigned u; } v; v.f = x;
  return (unsigned short)((v.u + 0x7fffu + ((v.u >> 16) & 1u)) >> 16);  // RNE
}

// ---------------- K1: gram partials + fragment-stream packing (Ptf, Pbf) ------------------
//  Ptf (phase1 B): frag (ch,it,t) idx=(ch*4+it)*4+t ; elem e = P[ch*128+it*32+quad*8+e][t*16+c16]
//  Pbf (apply A):  frag idx=2*ft+j (ft=16-f tile)   ; elem e = P[ft*16+c16][j*32+quad*8+e]
__global__ void pp_gram(const float* __restrict__ P, float* __restrict__ partial,
                        unsigned short* __restrict__ Ptf, unsigned short* __restrict__ Pbf) {
  __shared__ float Pl[64][68];
  const int tid = threadIdx.x, b = blockIdx.x;
  #pragma unroll
  for (int u = 0; u < 4; ++u) {
    const int f = tid >> 2, r = (tid & 3) * 16 + 4 * u;
    *(f32x4*)&Pl[f][r] = *(const f32x4*)(P + (size_t)(b * 64 + f) * 64 + r);
  }
  __syncthreads();

  // Ptf slice: this block covers f in [64b, 64b+64) -> ch=b>>1, it in {2(b&1), 2(b&1)+1}
  #pragma unroll
  for (int u = 0; u < 2; ++u) {
    const int flat = tid + 256 * u;          // 8 frags x 64 lanes
    const int lf = flat >> 6, lane = flat & 63;
    const int c16 = lane & 15, quad = lane >> 4;
    const int it_loc = lf >> 2, t = lf & 3;
    const int flb = it_loc * 32 + quad * 8;  // local f base
    bf16x8 w;
    #pragma unroll
    for (int e = 0; e < 8; ++e) w[e] = (short)bf16bits(Pl[flb + e][t * 16 + c16]);
    const int gidx = ((b >> 1) * 4 + 2 * (b & 1) + it_loc) * 4 + t;
    *(bf16x8*)(Ptf + ((size_t)gidx * 64 + lane) * 8) = w;
  }
  // Pbf slice: ft tiles 4b..4b+3 (local t2=0..3), frag idx = 2*ft+j
  #pragma unroll
  for (int u = 0; u < 2; ++u) {
    const int flat = tid + 256 * u;
    const int lf = flat >> 6, lane = flat & 63;
    const int c16 = lane & 15, quad = lane >> 4;
    const int t2 = lf >> 1, j = lf & 1;
    f32x4 p0 = *(const f32x4*)&Pl[t2 * 16 + c16][j * 32 + quad * 8];
    f32x4 p1 = *(const f32x4*)&Pl[t2 * 16 + c16][j * 32 + quad * 8 + 4];
    bf16x8 w;
    #pragma unroll
    for (int e = 0; e < 4; ++e) { w[e] = (short)bf16bits(p0[e]); w[4 + e] = (short)bf16bits(p1[e]); }
    const int gidx = 2 * (b * 4 + t2) + j;
    *(bf16x8*)(Pbf + ((size_t)gidx * 64 + lane) * 8) = w;
  }

  // gram partial: partial[b] = Pchunk^T @ Pchunk
  const int a0 = (tid >> 4) * 4, b0 = (tid & 15) * 4;
  f32x4 acc[4];
  #pragma unroll
  for (int i = 0; i < 4; ++i) acc[i] = (f32x4){0.f, 0.f, 0.f, 0.f};
  for (int k = 0; k < 64; ++k) {
    f32x4 av = *(const f32x4*)&Pl[k][a0];
    f32x4 bv = *(const f32x4*)&Pl[k][b0];
    #pragma unroll
    for (int i = 0; i < 4; ++i) acc[i] += av[i] * bv;
  }
  #pragma unroll
  for (int i = 0; i < 4; ++i)
    *(f32x4*)(partial + (size_t)b * 4096 + (size_t)(a0 + i) * 64 + b0) = acc[i];
}

// ---------------- helpers for phase 1 -----------------------------------------------------
__device__ __forceinline__ void ld_chunk(const float* __restrict__ hp, int ch, f32x4* v) {
  #pragma unroll
  for (int it = 0; it < 4; ++it) {
    v[2 * it] = *(const f32x4*)(hp + ch * 128 + it * 32);
    v[2 * it + 1] = *(const f32x4*)(hp + ch * 128 + it * 32 + 4);
  }
}

__device__ __forceinline__ void comp_chunk(const f32x4* v, const unsigned short* __restrict__ bp0,
                                           int ch, f32x4* accY, float& sqacc) {
  #pragma unroll
  for (int it = 0; it < 4; ++it) {
    const f32x4 v0 = v[2 * it], v1 = v[2 * it + 1];
    sqacc += v0[0] * v0[0] + v0[1] * v0[1] + v0[2] * v0[2] + v0[3] * v0[3] +
             v1[0] * v1[0] + v1[1] * v1[1] + v1[2] * v1[2] + v1[3] * v1[3];
    bf16x8 a;
    a[0] = (short)bf16bits(v0[0]); a[1] = (short)bf16bits(v0[1]);
    a[2] = (short)bf16bits(v0[2]); a[3] = (short)bf16bits(v0[3]);
    a[4] = (short)bf16bits(v1[0]); a[5] = (short)bf16bits(v1[1]);
    a[6] = (short)bf16bits(v1[2]); a[7] = (short)bf16bits(v1[3]);
    #pragma unroll
    for (int t = 0; t < 4; ++t) {  // B[k=f][n=r], k-contiguous frag stream
      bf16x8 b = *(const bf16x8*)(bp0 + (size_t)((ch * 4 + it) * 4 + t) * 512);
      accY[t] = MFMA_B16(a, b, accY[t]);
    }
  }
}

// ---------------- K2: fused — block 0 inverts; blocks 1..512 stream + apply ---------------
__global__ __launch_bounds__(256, 3) void pp_fused(
    const float* __restrict__ H, const float* __restrict__ partial,
    const unsigned short* __restrict__ Ptf, const unsigned short* __restrict__ Pbf,
    unsigned short* __restrict__ Wf, unsigned int* __restrict__ flag,
    float* __restrict__ out) {
  // union'd LDS: block 0 uses A[64][68] f32 (17408 B); workers use Yt/Ct/scT (18688 B)
  __shared__ __align__(16) unsigned char smem[18688];
  const int tid = threadIdx.x;
  const int lane = tid & 63, wid = tid >> 6;
  const int c16 = lane & 15, quad = lane >> 4;

  if (blockIdx.x == 0) {
    // ---- control block: G = sum partials; W = G^{-1} (4-wave GJ); emit Wf; release flag
    float (*A)[68] = (float(*)[68])smem;
    const int i = tid >> 2, q16 = (tid & 3) * 16;
    #pragma unroll
    for (int u = 0; u < 4; ++u) {
      f32x4 s = (f32x4){0.f, 0.f, 0.f, 0.f};
      const int off = i * 64 + q16 + 4 * u;
      for (int p = 0; p < 16; ++p) s += *(const f32x4*)(partial + (size_t)p * 4096 + off);
      *(f32x4*)&A[i][q16 + 4 * u] = s;
    }
    __syncthreads();
    for (int k = 0; k < 64; ++k) {
      const float d = 1.0f / A[k][k];
      const float f = A[i][k];
      f32x4 prs[4], cur[4];
      #pragma unroll
      for (int u = 0; u < 4; ++u) {
        prs[u] = *(const f32x4*)&A[k][q16 + 4 * u];
        cur[u] = *(const f32x4*)&A[i][q16 + 4 * u];
      }
      __syncthreads();  // all reads done before any writes
      const int kl = k - q16;
      #pragma unroll
      for (int u = 0; u < 4; ++u) {
        f32x4 pv = prs[u] * d;
        if (kl >= u * 4 && kl < u * 4 + 4) { pv[kl - u * 4] = d; cur[u][kl - u * 4] = 0.f; }
        f32x4 res = (i == k) ? pv : (cur[u] - f * pv);
        *(f32x4*)&A[i][q16 + 4 * u] = res;
      }
      __syncthreads();
    }
    // Wf frag stream: frag (kk,t) idx=kk*4+t ; elem e = W[kk*32+quad*8+e][t*16+c16]
    #pragma unroll
    for (int u = 0; u < 2; ++u) {
      const int flat = tid + 256 * u;
      const int lf = flat >> 6, ln = flat & 63;
      const int lc = ln & 15, lq = ln >> 4;
      const int kk = lf >> 2, tf = lf & 3;
      bf16x8 w;
      #pragma unroll
      for (int e = 0; e < 8; ++e) w[e] = (short)bf16bits(A[kk * 32 + lq * 8 + e][tf * 16 + lc]);
      *(bf16x8*)(Wf + ((size_t)(kk * 4 + tf) * 64 + ln) * 8) = w;
    }
    __threadfence();
    __syncthreads();
    if (tid == 0)
      __hip_atomic_store(flag, 1u, __ATOMIC_RELEASE, __HIP_MEMORY_SCOPE_AGENT);
    return;
  }

  // ---- worker block: rows [wb*64, wb*64+64) ----
  unsigned short (*Yt)[72] = (unsigned short(*)[72])smem;            // [64][72]
  unsigned short (*Ct)[72] = (unsigned short(*)[72])(smem + 9216);   // [64][72]
  float* scT = (float*)(smem + 18432);                               // [64]
  const int wb = blockIdx.x - 1;
  const int strip = wid * 16;
  const long row0 = (long)wb * 64;

  // phase 1: Y = H @ P (register-direct; Ptf ready via kernel boundary; overlaps invert)
  f32x4 accY[4];
  #pragma unroll
  for (int t = 0; t < 4; ++t) accY[t] = (f32x4){0.f, 0.f, 0.f, 0.f};
  float sqacc = 0.f;
  const float* hp = H + (row0 + strip + c16) * 1024 + quad * 8;
  const unsigned short* bp0 = Ptf + lane * 8;
  {
    f32x4 va[8], vb[8];
    ld_chunk(hp, 0, va);
    ld_chunk(hp, 1, vb);
    comp_chunk(va, bp0, 0, accY, sqacc); ld_chunk(hp, 2, va);
    comp_chunk(vb, bp0, 1, accY, sqacc); ld_chunk(hp, 3, vb);
    comp_chunk(va, bp0, 2, accY, sqacc); ld_chunk(hp, 4, va);
    comp_chunk(vb, bp0, 3, accY, sqacc); ld_chunk(hp, 5, vb);
    comp_chunk(va, bp0, 4, accY, sqacc); ld_chunk(hp, 6, va);
    comp_chunk(vb, bp0, 5, accY, sqacc); ld_chunk(hp, 7, vb);
    comp_chunk(va, bp0, 6, accY, sqacc);
    comp_chunk(vb, bp0, 7, accY, sqacc);
  }

  // row sum-of-squares: reduce across quads (lane row = strip + c16)
  sqacc += __shfl_xor(sqacc, 16);
  sqacc += __shfl_xor(sqacc, 32);

  // Y -> wave-private LDS (bf16); intra-wave RAW ordered via lgkmcnt
  #pragma unroll
  for (int t = 0; t < 4; ++t)
    #pragma unroll
    for (int r = 0; r < 4; ++r)  // D layout: col = lane&15, row = quad*4+reg
      Yt[strip + quad * 4 + r][t * 16 + c16] = bf16bits(accY[t][r]);

  // wait for W (usually already published by now)
  if (tid == 0) {
    while (__hip_atomic_load(flag, __ATOMIC_ACQUIRE, __HIP_MEMORY_SCOPE_AGENT) == 0u)
      __builtin_amdgcn_s_sleep(2);
  }
  __syncthreads();
  __threadfence();

  // phase 2: C = Y @ W (Wf frag stream)
  f32x4 accC[4];
  #pragma unroll
  for (int t = 0; t < 4; ++t) accC[t] = (f32x4){0.f, 0.f, 0.f, 0.f};
  #pragma unroll
  for (int kk = 0; kk < 2; ++kk) {
    bf16x8 a = *(const bf16x8*)&Yt[strip + c16][kk * 32 + quad * 8];
    #pragma unroll
    for (int t = 0; t < 4; ++t) {
      bf16x8 b = *(const bf16x8*)(Wf + ((size_t)(kk * 4 + t) * 64 + lane) * 8);
      accC[t] = MFMA_B16(a, b, accC[t]);
    }
  }
  #pragma unroll
  for (int t = 0; t < 4; ++t)
    #pragma unroll
    for (int r = 0; r < 4; ++r)
      Ct[strip + quad * 4 + r][t * 16 + c16] = bf16bits(accC[t][r]);

  // per-row dot = y.c, scale = sqrt(o2/(o2-dot)); publish to wave-private scT
  #pragma unroll
  for (int r = 0; r < 4; ++r) {
    float dd = accY[0][r] * accC[0][r] + accY[1][r] * accC[1][r] +
               accY[2][r] * accC[2][r] + accY[3][r] * accC[3][r];
    dd += __shfl_xor(dd, 1);
    dd += __shfl_xor(dd, 2);
    dd += __shfl_xor(dd, 4);
    dd += __shfl_xor(dd, 8);
    const float o2 = __shfl(sqacc, quad * 4 + r);
    if (c16 == 0) {
      const float n2 = fmaxf(o2 - dd, 1e-30f);
      scT[strip + quad * 4 + r] = sqrtf(o2 / n2);
    }
  }

  // phase 3: out = (H - C @ P^T) * scale. Swapped operands: A=Pbf frag, B=C frag -> D f-major.
  bf16x8 cb0 = *(const bf16x8*)&Ct[strip + c16][quad * 8];       // B[k=r][m], k in [0,32)
  bf16x8 cb1 = *(const bf16x8*)&Ct[strip + c16][32 + quad * 8];  // k in [32,64)
  const long grow = row0 + strip + c16;       // this lane's output row
  const float sc = scT[strip + c16];
  const bool fs = ((grow & 4095) == 0);       // s==0 rows pass through exactly
  const float* hp2 = H + grow * 1024 + quad * 4;
  float* op = out + grow * 1024 + quad * 4;
  const unsigned short* pb = Pbf + lane * 8;  // frag idx 2*ft+j, stride 512 shorts

  f32x4 hbuf[4];
  bf16x8 abuf[2][2];
  #pragma unroll
  for (int i2 = 0; i2 < 4; ++i2) hbuf[i2] = *(const f32x4*)(hp2 + (size_t)i2 * 16);
  #pragma unroll
  for (int i2 = 0; i2 < 2; ++i2) {
    abuf[i2][0] = *(const bf16x8*)(pb + (size_t)(2 * i2 + 0) * 512);
    abuf[i2][1] = *(const bf16x8*)(pb + (size_t)(2 * i2 + 1) * 512);
  }

  #pragma unroll 4
  for (int ft = 0; ft < 64; ++ft) {
    const f32x4 hcur = hbuf[ft & 3];
    const bf16x8 pa0 = abuf[ft & 1][0];
    const bf16x8 pa1 = abuf[ft & 1][1];
    if (ft + 4 < 64) hbuf[ft & 3] = *(const f32x4*)(hp2 + (size_t)(ft + 4) * 16);
    if (ft + 2 < 64) {
      abuf[ft & 1][0] = *(const bf16x8*)(pb + (size_t)(2 * (ft + 2) + 0) * 512);
      abuf[ft & 1][1] = *(const bf16x8*)(pb + (size_t)(2 * (ft + 2) + 1) * 512);
    }
    f32x4 acc = (f32x4){0.f, 0.f, 0.f, 0.f};
    acc = MFMA_B16(pa0, cb0, acc);
    acc = MFMA_B16(pa1, cb1, acc);
    f32x4 o;
    #pragma unroll
    for (int e = 0; e < 4; ++e) o[e] = (hcur[e] - acc[e]) * sc;
    if (fs) o = hcur;
    *(f32x4*)(op + (size_t)ft * 16) = o;
  }
}

extern "C" void kernel_launch(void* const* d_in, const int* in_sizes, int n_in,
                              void* d_out, int out_size, void* d_ws, size_t ws_size,
                              hipStream_t stream) {
  const float* H = (const float*)d_in[0];   // 8*4096*1024 fp32
  const float* P = (const float*)d_in[1];   // 1024*64 fp32
  float* out = (float*)d_out;
  // ws: partial f32[65536] | Ptf u16[65536] | Pbf u16[65536] | Wf u16[4096] | flag u32
  float* partial = (float*)d_ws;
  unsigned short* Ptf = (unsigned short*)(partial + 16 * 4096);
  unsigned short* Pbf = Ptf + 65536;
  unsigned short* Wf = Pbf + 65536;
  unsigned int* flag = (unsigned int*)(Wf + 4096);

  hipMemsetAsync(flag, 0, sizeof(unsigned int), stream);
  pp_gram<<<16, 256, 0, stream>>>(P, partial, Ptf, Pbf);
  pp_fused<<<513, 256, 0, stream>>>(H, partial, Ptf, Pbf, Wf, flag, out);
}